// Round 1
// 429.785 us; speedup vs baseline: 1.1805x; 1.1805x over previous
//
#include <hip/hip_runtime.h>

// HGCN forward (2-layer hyperbolic GCN), Poincare ball c=1. fp32 in/out
// (values bf16-grid). Round 11 = round 10 with:
//  (a) tier-A CSR build: count records rank[e]=atomicAdd(deg[d],1) (coalesced
//      store); fill places csr[rowst[d]+rank[e]] with ZERO atomics (halves
//      total atomics, breaks fill's ld->atomic->st chain). Needs +4E B of ws
//      (rank); three-tier gate A -> B(round-10, proven) -> fallback.
//  (b) paired bf16x2 gathers: half-wave per row, u32 loads carry 2 dims/lane;
//      one load = 2 rows in flight, shuffles halved, ILP 4 pairs = 8 rows.
//  (c) single-block scan kernel also runs 512 layer1 tile-blocks (4 virtual
//      256-thr groups per 1024-thr block); fused fill kernel takes the rest,
//      parity-interleaved with fill blocks for true co-residency.

#define EPSV 1e-15f
#define MAXN 0.996f   // (1 - 4e-3) / sqrt(c), c = 1

typedef unsigned short bfu;
typedef __attribute__((ext_vector_type(8))) short v8s;   // 8 bf16 (4 VGPRs)
typedef __attribute__((ext_vector_type(4))) float v4f;   // MFMA acc

__device__ __forceinline__ bfu f2b(float f) {   // fp32 -> bf16, RNE
    unsigned int u;
    __builtin_memcpy(&u, &f, sizeof(u));
    u += 0x7fffu + ((u >> 16) & 1u);
    return (bfu)(u >> 16);
}

__device__ __forceinline__ float b2f(bfu s) {
    unsigned int u = ((unsigned int)s) << 16;
    float f;
    __builtin_memcpy(&f, &u, sizeof(f));
    return f;
}

// low/high bf16 of a packed u32 -> fp32
__device__ __forceinline__ float uplo(unsigned int u) {
    unsigned int v = u << 16; float f;
    __builtin_memcpy(&f, &v, sizeof(f)); return f;
}
__device__ __forceinline__ float uphi(unsigned int u) {
    unsigned int v = u & 0xffff0000u; float f;
    __builtin_memcpy(&f, &v, sizeof(f)); return f;
}

__device__ __forceinline__ v8s cvt8(const float* f) {
    v8s r;
#pragma unroll
    for (int j = 0; j < 8; ++j) r[j] = (short)f2b(f[j]);
    return r;
}

__device__ __forceinline__ float i2f(int i) {
    float f; __builtin_memcpy(&f, &i, sizeof(f)); return f;
}
__device__ __forceinline__ int f2i(float f) {
    int i; __builtin_memcpy(&i, &f, sizeof(i)); return i;
}

__device__ __forceinline__ float wredsum(float v) {
#pragma unroll
    for (int o = 32; o > 0; o >>= 1) v += __shfl_xor(v, o, 64);
    return v;
}

// reduce within each 32-lane half (enough when both halves hold all dims)
__device__ __forceinline__ float hredsum(float v) {
#pragma unroll
    for (int o = 16; o > 0; o >>= 1) v += __shfl_xor(v, o, 64);
    return v;
}

__device__ __forceinline__ float artanh_(float x) {
    x = fminf(fmaxf(x, -1.0f + 1e-7f), 1.0f - 1e-7f);
    return 0.5f * logf((1.0f + x) / (1.0f - x));
}

__device__ __forceinline__ float mobius_tail(float mx, float xn, float hb, float y2) {
    float mxn2 = wredsum(mx * mx);
    unsigned long long nz = __ballot(mx != 0.0f);
    float mxn = fmaxf(sqrtf(mxn2), EPSV);
    float rt = tanhf(mxn / xn * artanh_(xn));
    float mv, x2s;
    if (nz != 0ull) {
        mv = (rt / mxn) * mx;
        float mvn = fmaxf(fabsf(rt), EPSV);
        if (mvn > MAXN) mv *= MAXN / mvn;
        float cn = fminf(mvn, MAXN);
        x2s = cn * cn;
    } else { mv = 0.0f; x2s = 0.0f; }
    float xy = wredsum(mv * hb);
    float ca = 1.0f + 2.0f * xy + y2;
    float cb = 1.0f - x2s;
    float den = fmaxf(1.0f + 2.0f * xy + x2s * y2, EPSV);
    float hj = (ca * mv + cb * hb) / den;
    float hn = fmaxf(sqrtf(wredsum(hj * hj)), EPSV);
    if (hn > MAXN) { hj *= MAXN / hn; hn = MAXN; }
    return (artanh_(hn) / hn) * hj;
}

__device__ __forceinline__ float agg_transform(float a, float* xn_out) {
    float n = fmaxf(sqrtf(wredsum(a * a)), EPSV);
    float th = tanhf(n);
    float g = th / n;
    float nh = fmaxf(th, EPSV);
    if (nh > MAXN) { g *= MAXN / nh; nh = MAXN; }
    float h = g * a;
    float t = fmaxf((artanh_(nh) / nh) * h, 0.0f);
    float n2 = fmaxf(sqrtf(wredsum(t * t)), EPSV);
    float th2 = tanhf(n2);
    float g2 = th2 / n2;
    float nh2 = fmaxf(th2, EPSV);
    if (nh2 > MAXN) { g2 *= MAXN / nh2; nh2 = MAXN; }
    *xn_out = nh2;
    return g2 * t;
}

__device__ __forceinline__ float bias_point(const float* bv, int lane, float* y2) {
    float b = bv[lane];
    float bn = fmaxf(sqrtf(wredsum(b * b)), EPSV);
    float gs = tanhf(bn) / bn;
    float hbn = fmaxf(tanhf(bn), EPSV);
    if (hbn > MAXN) gs *= MAXN / hbn;
    float hb = gs * b;
    *y2 = wredsum(hb * hb);
    return hb;
}

__global__ __launch_bounds__(256) void hgA_zero(float* __restrict__ p, int n4) {
    const float4 z = make_float4(0.f, 0.f, 0.f, 0.f);
    int stride = gridDim.x * blockDim.x;
    for (int i = blockIdx.x * blockDim.x + threadIdx.x; i < n4; i += stride)
        ((float4*)p)[i] = z;
}

// ===== layer1 body (MFMA, proven) -- writes bf16 xt. tid in [0,256) =====
__device__ __forceinline__ void layer1_body(
    int bid, int tid, const float* __restrict__ x, const float* __restrict__ W1,
    const float* __restrict__ b1v, bfu* __restrict__ xtb, int N)
{
    const int lane = tid & 63, wv = tid >> 6;
    const int nodeBase = (bid * 4 + wv) * 16;
    if (nodeBase >= N) return;

    float y2;
    float hb = bias_point(b1v, lane, &y2);
    float hbv[4];
#pragma unroll
    for (int t = 0; t < 4; ++t) hbv[t] = __shfl(hb, (lane & 15) + 16 * t);

    const int m = lane & 15, q = lane >> 4;
    v4f acc0 = {0,0,0,0}, acc1 = {0,0,0,0}, acc2 = {0,0,0,0}, acc3 = {0,0,0,0};
    float usq = 0.0f;

    const float* arow = x + (size_t)(nodeBase + m) * 256 + q * 8;
#pragma unroll
    for (int s = 0; s < 8; ++s) {
        float af[8];
        *(float4*)(af)     = *(const float4*)(arow + s * 32);
        *(float4*)(af + 4) = *(const float4*)(arow + s * 32 + 4);
#pragma unroll
        for (int j = 0; j < 8; ++j) usq = fmaf(af[j], af[j], usq);
        v8s a = cvt8(af);
        const float* wbase = W1 + (size_t)m * 256 + s * 32 + q * 8;
        float wf[8];
        *(float4*)(wf) = *(const float4*)(wbase);
        *(float4*)(wf + 4) = *(const float4*)(wbase + 4);
        acc0 = __builtin_amdgcn_mfma_f32_16x16x32_bf16(a, cvt8(wf), acc0, 0, 0, 0);
        *(float4*)(wf) = *(const float4*)(wbase + 16 * 256);
        *(float4*)(wf + 4) = *(const float4*)(wbase + 16 * 256 + 4);
        acc1 = __builtin_amdgcn_mfma_f32_16x16x32_bf16(a, cvt8(wf), acc1, 0, 0, 0);
        *(float4*)(wf) = *(const float4*)(wbase + 32 * 256);
        *(float4*)(wf + 4) = *(const float4*)(wbase + 32 * 256 + 4);
        acc2 = __builtin_amdgcn_mfma_f32_16x16x32_bf16(a, cvt8(wf), acc2, 0, 0, 0);
        *(float4*)(wf) = *(const float4*)(wbase + 48 * 256);
        *(float4*)(wf + 4) = *(const float4*)(wbase + 48 * 256 + 4);
        acc3 = __builtin_amdgcn_mfma_f32_16x16x32_bf16(a, cvt8(wf), acc3, 0, 0, 0);
    }
    usq += __shfl_xor(usq, 16, 64);
    usq += __shfl_xor(usq, 32, 64);

    float P[4], Q[4];
#pragma unroll
    for (int r = 0; r < 4; ++r) {
        float s2 = acc0[r]*acc0[r] + acc1[r]*acc1[r] + acc2[r]*acc2[r] + acc3[r]*acc3[r];
        float sh = acc0[r]*hbv[0] + acc1[r]*hbv[1] + acc2[r]*hbv[2] + acc3[r]*hbv[3];
#pragma unroll
        for (int o = 1; o < 16; o <<= 1) {
            s2 += __shfl_xor(s2, o, 64);
            sh += __shfl_xor(sh, o, 64);
        }
        float usq_r = __shfl(usq, q * 4 + r);
        float n  = fmaxf(sqrtf(usq_r), EPSV);
        float th = tanhf(n);
        float gamma = th / n;
        float xn = fmaxf(th, EPSV);
        if (xn > MAXN) { gamma *= MAXN / xn; xn = MAXN; }
        float mxn = fmaxf(gamma * sqrtf(s2), EPSV);
        float rt  = tanhf(mxn / xn * artanh_(xn));
        float k1, x2s, xy;
        if (s2 != 0.0f) {
            k1 = (rt / mxn) * gamma;
            float mvn = fmaxf(fabsf(rt), EPSV);
            if (mvn > MAXN) k1 *= MAXN / mvn;
            float cn = fminf(mvn, MAXN);
            x2s = cn * cn;
            xy  = k1 * sh;
        } else { k1 = 0.0f; x2s = 0.0f; xy = 0.0f; }
        float ca = 1.0f + 2.0f * xy + y2;
        float cb = 1.0f - x2s;
        float den = fmaxf(1.0f + 2.0f * xy + x2s * y2, EPSV);
        float hn2 = ca*ca*x2s + 2.0f*ca*cb*xy + cb*cb*y2;
        float hn = fmaxf(sqrtf(hn2) / den, EPSV);
        float hs = 1.0f;
        if (hn > MAXN) { hs = MAXN / hn; hn = MAXN; }
        float lam = artanh_(hn) / hn;
        P[r] = lam * hs * ca * k1 / den;
        Q[r] = lam * hs * cb / den;
    }
#pragma unroll
    for (int r = 0; r < 4; ++r) {
        bfu* orow = xtb + (size_t)(nodeBase + q * 4 + r) * 64 + m;
        orow[ 0] = f2b(P[r] * acc0[r] + Q[r] * hbv[0]);
        orow[16] = f2b(P[r] * acc1[r] + Q[r] * hbv[1]);
        orow[32] = f2b(P[r] * acc2[r] + Q[r] * hbv[2]);
        orow[48] = f2b(P[r] * acc3[r] + Q[r] * hbv[3]);
    }
}

// ===== CSR build =====
__global__ __launch_bounds__(256) void hgA_zero_i32(int* __restrict__ p, int n) {
    int stride = gridDim.x * blockDim.x;
    for (int i = blockIdx.x * blockDim.x + threadIdx.x; i < n; i += stride) p[i] = 0;
}

// tier B count (no rank)
__global__ __launch_bounds__(256) void hgA_count(
    const int* __restrict__ dst, int* __restrict__ deg, int E) {
    int stride = gridDim.x * blockDim.x;
    for (int e = blockIdx.x * blockDim.x + threadIdx.x; e < E; e += stride)
        atomicAdd(&deg[dst[e]], 1);
}

// tier A count: record per-edge rank (coalesced store); only atomic pass
__global__ __launch_bounds__(256) void hgA_count_rank(
    const int* __restrict__ dst, int* __restrict__ deg,
    int* __restrict__ rank, int E) {
    int stride = gridDim.x * blockDim.x;
    for (int e = blockIdx.x * blockDim.x + threadIdx.x; e < E; e += stride)
        rank[e] = atomicAdd(&deg[dst[e]], 1);
}

// block 0: exclusive scan of deg -> row_start (+cursor). blocks >0: layer1
// tile-blocks [0, NL) as 4 virtual 256-thread groups per 1024-thread block.
__global__ __launch_bounds__(1024) void hgA_scan_l1(
    const int* __restrict__ deg, int* __restrict__ row_start,
    int* __restrict__ cursor, int N,
    const float* __restrict__ x, const float* __restrict__ W1,
    const float* __restrict__ b1v, bfu* __restrict__ xtb, int NL)
{
    if (blockIdx.x != 0) {
        int vb = (blockIdx.x - 1) * 4 + (threadIdx.x >> 8);
        if (vb < NL) layer1_body(vb, threadIdx.x & 255, x, W1, b1v, xtb, N);
        return;
    }
    __shared__ int wsum[16];
    __shared__ int srun;
    const int tid = threadIdx.x, lane = tid & 63, wv = tid >> 6;
    if (tid == 0) srun = 0;
    __syncthreads();
    for (int base = 0; base < N; base += 1024) {
        int i = base + tid;
        int v = (i < N) ? deg[i] : 0;
        int incl = v;
#pragma unroll
        for (int o = 1; o < 64; o <<= 1) {
            int nbr = __shfl_up(incl, o, 64);
            if (lane >= o) incl += nbr;
        }
        if (lane == 63) wsum[wv] = incl;
        __syncthreads();
        int add = 0;
#pragma unroll
        for (int w = 0; w < 16; ++w) { int s = wsum[w]; if (w < wv) add += s; }
        int excl = srun + add + incl - v;
        if (i < N) { row_start[i] = excl; cursor[i] = excl; }
        __syncthreads();
        if (tid == 1023) srun += add + incl;
        __syncthreads();
    }
    if (tid == 0) row_start[N] = srun;
}

// ===== tier B fused: fill (atomic cursor) || layer1, round-10 proven =====
__global__ __launch_bounds__(256) void hgA_fill_layer1(
    const int* __restrict__ src, const int* __restrict__ dst,
    const float* __restrict__ ew, int* __restrict__ cursor,
    int2* __restrict__ csr, int E, int fillBlocks,
    const float* __restrict__ x, const float* __restrict__ W1,
    const float* __restrict__ b1v, bfu* __restrict__ xtb, int N)
{
    const int b = blockIdx.x;
    if (b < fillBlocks) {
        int stride = fillBlocks * blockDim.x;
        for (int e = b * blockDim.x + threadIdx.x; e < E; e += stride) {
            int d = dst[e];
            int slot = atomicAdd(&cursor[d], 1);
            csr[slot] = make_int2(src[e], f2i(ew[e]));
        }
    } else {
        layer1_body(b - fillBlocks, threadIdx.x, x, W1, b1v, xtb, N);
    }
}

// ===== tier A fused: atomic-free fill || layer1 tail, parity-interleaved =====
// nf fill virtual-blocks, nl layer virtual-blocks (bids l1off + [0,nl))
__global__ __launch_bounds__(256) void hgA_fillr_layer1(
    const int* __restrict__ src, const int* __restrict__ dst,
    const float* __restrict__ ew, const int* __restrict__ rank,
    const int* __restrict__ row_start, int2* __restrict__ csr,
    int E, int nf, int nl, int l1off,
    const float* __restrict__ x, const float* __restrict__ W1,
    const float* __restrict__ b1v, bfu* __restrict__ xtb, int N)
{
    const int b = blockIdx.x;
    const int mn = nf < nl ? nf : nl;
    bool isFill; int idx;
    if (b < 2 * mn) { isFill = !(b & 1); idx = b >> 1; }
    else            { isFill = (nf > nl); idx = mn + (b - 2 * mn); }
    if (isFill) {
        int stride = nf * 256;
        for (int e = idx * 256 + threadIdx.x; e < E; e += stride) {
            int d = dst[e];
            csr[row_start[d] + rank[e]] = make_int2(src[e], f2i(ew[e]));
        }
    } else {
        layer1_body(l1off + idx, threadIdx.x, x, W1, b1v, xtb, N);
    }
}

// ===== gather #1: agg[d] = sum w*xtb[src]; paired bf16x2 (2 rows / load) =====
__global__ __launch_bounds__(256) void hgA_gather(
    const int* __restrict__ row_start, const int2* __restrict__ csr,
    const bfu* __restrict__ xtb, float* __restrict__ agg, int N) {
    const int lane = threadIdx.x & 63, wv = threadIdx.x >> 6;
    const int d = blockIdx.x * 4 + wv;
    if (d >= N) return;
    const int sl = lane & 31, p = lane >> 5;
    const int n0 = row_start[d], n1 = row_start[d + 1];
    const unsigned int* xt32 = (const unsigned int*)xtb;
    float a0x = 0.f, a0y = 0.f, a1x = 0.f, a1y = 0.f;
    float a2x = 0.f, a2y = 0.f, a3x = 0.f, a3y = 0.f;
    for (int base = n0; base < n1; base += 64) {
        int cnt = n1 - base; if (cnt > 64) cnt = 64;
        int sL = 0; float wL = 0.0f;   // lanes >= cnt keep s=0, w=0 (safe pad)
        if (lane < cnt) { int2 rec = csr[base + lane]; sL = rec.x; wL = i2f(rec.y); }
        int j = 0;
        for (; j + 8 <= cnt; j += 8) {
            int   s0 = __shfl(sL, j     + p, 64), s1 = __shfl(sL, j + 2 + p, 64);
            int   s2 = __shfl(sL, j + 4 + p, 64), s3 = __shfl(sL, j + 6 + p, 64);
            float w0 = __shfl(wL, j     + p, 64), w1 = __shfl(wL, j + 2 + p, 64);
            float w2 = __shfl(wL, j + 4 + p, 64), w3 = __shfl(wL, j + 6 + p, 64);
            unsigned int u0 = xt32[(size_t)s0 * 32 + sl];
            unsigned int u1 = xt32[(size_t)s1 * 32 + sl];
            unsigned int u2 = xt32[(size_t)s2 * 32 + sl];
            unsigned int u3 = xt32[(size_t)s3 * 32 + sl];
            a0x = fmaf(w0, uplo(u0), a0x); a0y = fmaf(w0, uphi(u0), a0y);
            a1x = fmaf(w1, uplo(u1), a1x); a1y = fmaf(w1, uphi(u1), a1y);
            a2x = fmaf(w2, uplo(u2), a2x); a2y = fmaf(w2, uphi(u2), a2y);
            a3x = fmaf(w3, uplo(u3), a3x); a3y = fmaf(w3, uphi(u3), a3y);
        }
        for (; j < cnt; j += 2) {       // tail (odd edge pairs with w=0 pad)
            int   s = __shfl(sL, j + p, 64);
            float w = __shfl(wL, j + p, 64);
            unsigned int u = xt32[(size_t)s * 32 + sl];
            a0x = fmaf(w, uplo(u), a0x); a0y = fmaf(w, uphi(u), a0y);
        }
    }
    float tx = (a0x + a1x) + (a2x + a3x);
    float ty = (a0y + a1y) + (a2y + a3y);
    tx += __shfl_xor(tx, 32, 64);
    ty += __shfl_xor(ty, 32, 64);
    if (p == 0)
        *(float2*)(agg + (size_t)d * 64 + 2 * sl) = make_float2(tx, ty);
}

// ===== layer 2: MFMA fused HypAct+matvec+tail; agg(d_out) -> xtb2(ws, bf16) =====
__global__ __launch_bounds__(256) void hgA_layer2_mfma(
    const float* __restrict__ agg,   // [N,64] fp32 (d_out)
    const float* __restrict__ W2,    // [64,64] row-major
    const float* __restrict__ b2v,   // [64]
    bfu* __restrict__ xtb2, int N)   // [N,64] bf16 (ws)
{
    const int tid = threadIdx.x, lane = tid & 63, wv = tid >> 6;
    const int nodeBase = (blockIdx.x * 4 + wv) * 16;
    if (nodeBase >= N) return;

    float y2;
    float hb = bias_point(b2v, lane, &y2);
    float hbv[4];
#pragma unroll
    for (int t = 0; t < 4; ++t) hbv[t] = __shfl(hb, (lane & 15) + 16 * t);

    const int m = lane & 15, q = lane >> 4;
    const bool rowok = (nodeBase + m) < N;

    float af0[8], af1[8];
    const float* arow = agg + (size_t)(nodeBase + m) * 64 + q * 8;
    if (rowok) {
        *(float4*)(af0)     = *(const float4*)(arow);
        *(float4*)(af0 + 4) = *(const float4*)(arow + 4);
        *(float4*)(af1)     = *(const float4*)(arow + 32);
        *(float4*)(af1 + 4) = *(const float4*)(arow + 36);
    } else {
#pragma unroll
        for (int j = 0; j < 8; ++j) { af0[j] = 0.0f; af1[j] = 0.0f; }
    }
    float asq = 0.0f;
#pragma unroll
    for (int j = 0; j < 8; ++j) {
        asq = fmaf(af0[j], af0[j], asq);
        asq = fmaf(af1[j], af1[j], asq);
    }
    asq += __shfl_xor(asq, 16, 64);
    asq += __shfl_xor(asq, 32, 64);

    float n  = fmaxf(sqrtf(asq), EPSV);
    float th = tanhf(n);
    float g  = th / n;
    float nh = fmaxf(th, EPSV);
    if (nh > MAXN) { g *= MAXN / nh; nh = MAXN; }
    float lamg = (artanh_(nh) / nh) * g;
    float t0[8], t1[8], tsq = 0.0f;
#pragma unroll
    for (int j = 0; j < 8; ++j) {
        t0[j] = fmaxf(lamg * af0[j], 0.0f);
        t1[j] = fmaxf(lamg * af1[j], 0.0f);
        tsq = fmaf(t0[j], t0[j], tsq);
        tsq = fmaf(t1[j], t1[j], tsq);
    }
    tsq += __shfl_xor(tsq, 16, 64);
    tsq += __shfl_xor(tsq, 32, 64);
    float n2  = fmaxf(sqrtf(tsq), EPSV);
    float th2 = tanhf(n2);
    float g2  = th2 / n2;
    float nh2 = fmaxf(th2, EPSV);
    if (nh2 > MAXN) { g2 *= MAXN / nh2; nh2 = MAXN; }
    float xn_m = nh2;
    float x0[8], x1[8];
#pragma unroll
    for (int j = 0; j < 8; ++j) { x0[j] = g2 * t0[j]; x1[j] = g2 * t1[j]; }
    v8s a0 = cvt8(x0), a1 = cvt8(x1);

    v4f acc0 = {0,0,0,0}, acc1 = {0,0,0,0}, acc2 = {0,0,0,0}, acc3 = {0,0,0,0};
    {
        float wf[8];
        const float* wb;
        wb = W2 + (size_t)(m     ) * 64 + q * 8;
        *(float4*)(wf) = *(const float4*)(wb);     *(float4*)(wf+4) = *(const float4*)(wb+4);
        acc0 = __builtin_amdgcn_mfma_f32_16x16x32_bf16(a0, cvt8(wf), acc0, 0, 0, 0);
        *(float4*)(wf) = *(const float4*)(wb+32);  *(float4*)(wf+4) = *(const float4*)(wb+36);
        acc0 = __builtin_amdgcn_mfma_f32_16x16x32_bf16(a1, cvt8(wf), acc0, 0, 0, 0);
        wb = W2 + (size_t)(m + 16) * 64 + q * 8;
        *(float4*)(wf) = *(const float4*)(wb);     *(float4*)(wf+4) = *(const float4*)(wb+4);
        acc1 = __builtin_amdgcn_mfma_f32_16x16x32_bf16(a0, cvt8(wf), acc1, 0, 0, 0);
        *(float4*)(wf) = *(const float4*)(wb+32);  *(float4*)(wf+4) = *(const float4*)(wb+36);
        acc1 = __builtin_amdgcn_mfma_f32_16x16x32_bf16(a1, cvt8(wf), acc1, 0, 0, 0);
        wb = W2 + (size_t)(m + 32) * 64 + q * 8;
        *(float4*)(wf) = *(const float4*)(wb);     *(float4*)(wf+4) = *(const float4*)(wb+4);
        acc2 = __builtin_amdgcn_mfma_f32_16x16x32_bf16(a0, cvt8(wf), acc2, 0, 0, 0);
        *(float4*)(wf) = *(const float4*)(wb+32);  *(float4*)(wf+4) = *(const float4*)(wb+36);
        acc2 = __builtin_amdgcn_mfma_f32_16x16x32_bf16(a1, cvt8(wf), acc2, 0, 0, 0);
        wb = W2 + (size_t)(m + 48) * 64 + q * 8;
        *(float4*)(wf) = *(const float4*)(wb);     *(float4*)(wf+4) = *(const float4*)(wb+4);
        acc3 = __builtin_amdgcn_mfma_f32_16x16x32_bf16(a0, cvt8(wf), acc3, 0, 0, 0);
        *(float4*)(wf) = *(const float4*)(wb+32);  *(float4*)(wf+4) = *(const float4*)(wb+36);
        acc3 = __builtin_amdgcn_mfma_f32_16x16x32_bf16(a1, cvt8(wf), acc3, 0, 0, 0);
    }

    float P[4], Q[4];
#pragma unroll
    for (int r = 0; r < 4; ++r) {
        float s2 = acc0[r]*acc0[r] + acc1[r]*acc1[r] + acc2[r]*acc2[r] + acc3[r]*acc3[r];
        float sh = acc0[r]*hbv[0] + acc1[r]*hbv[1] + acc2[r]*hbv[2] + acc3[r]*hbv[3];
#pragma unroll
        for (int o = 1; o < 16; o <<= 1) {
            s2 += __shfl_xor(s2, o, 64);
            sh += __shfl_xor(sh, o, 64);
        }
        float xn = __shfl(xn_m, q * 4 + r);
        float mxn = fmaxf(sqrtf(s2), EPSV);
        float rt  = tanhf(mxn / xn * artanh_(xn));
        float k1, x2s, xy;
        if (s2 != 0.0f) {
            k1 = rt / mxn;
            float mvn = fmaxf(fabsf(rt), EPSV);
            if (mvn > MAXN) k1 *= MAXN / mvn;
            float cn = fminf(mvn, MAXN);
            x2s = cn * cn;
            xy  = k1 * sh;
        } else { k1 = 0.0f; x2s = 0.0f; xy = 0.0f; }
        float ca = 1.0f + 2.0f * xy + y2;
        float cb = 1.0f - x2s;
        float den = fmaxf(1.0f + 2.0f * xy + x2s * y2, EPSV);
        float hn2 = ca*ca*x2s + 2.0f*ca*cb*xy + cb*cb*y2;
        float hn = fmaxf(sqrtf(hn2) / den, EPSV);
        float hs = 1.0f;
        if (hn > MAXN) { hs = MAXN / hn; hn = MAXN; }
        float lam = artanh_(hn) / hn;
        P[r] = lam * hs * ca * k1 / den;
        Q[r] = lam * hs * cb / den;
    }
#pragma unroll
    for (int r = 0; r < 4; ++r) {
        int ri = nodeBase + q * 4 + r;
        if (ri < N) {
            bfu* orow = xtb2 + (size_t)ri * 64 + m;
            orow[ 0] = f2b(P[r] * acc0[r] + Q[r] * hbv[0]);
            orow[16] = f2b(P[r] * acc1[r] + Q[r] * hbv[1]);
            orow[32] = f2b(P[r] * acc2[r] + Q[r] * hbv[2]);
            orow[48] = f2b(P[r] * acc3[r] + Q[r] * hbv[3]);
        }
    }
}

// ===== gather #2 + final HypAct fused; paired bf16x2 =====
__global__ __launch_bounds__(256) void hgA_gather_out(
    const int* __restrict__ row_start, const int2* __restrict__ csr,
    const bfu* __restrict__ xtb2, float* __restrict__ out, int N) {
    const int lane = threadIdx.x & 63, wv = threadIdx.x >> 6;
    const int d = blockIdx.x * 4 + wv;
    if (d >= N) return;
    const int sl = lane & 31, p = lane >> 5;
    const int n0 = row_start[d], n1 = row_start[d + 1];
    const unsigned int* xt32 = (const unsigned int*)xtb2;
    float a0x = 0.f, a0y = 0.f, a1x = 0.f, a1y = 0.f;
    float a2x = 0.f, a2y = 0.f, a3x = 0.f, a3y = 0.f;
    for (int base = n0; base < n1; base += 64) {
        int cnt = n1 - base; if (cnt > 64) cnt = 64;
        int sL = 0; float wL = 0.0f;
        if (lane < cnt) { int2 rec = csr[base + lane]; sL = rec.x; wL = i2f(rec.y); }
        int j = 0;
        for (; j + 8 <= cnt; j += 8) {
            int   s0 = __shfl(sL, j     + p, 64), s1 = __shfl(sL, j + 2 + p, 64);
            int   s2 = __shfl(sL, j + 4 + p, 64), s3 = __shfl(sL, j + 6 + p, 64);
            float w0 = __shfl(wL, j     + p, 64), w1 = __shfl(wL, j + 2 + p, 64);
            float w2 = __shfl(wL, j + 4 + p, 64), w3 = __shfl(wL, j + 6 + p, 64);
            unsigned int u0 = xt32[(size_t)s0 * 32 + sl];
            unsigned int u1 = xt32[(size_t)s1 * 32 + sl];
            unsigned int u2 = xt32[(size_t)s2 * 32 + sl];
            unsigned int u3 = xt32[(size_t)s3 * 32 + sl];
            a0x = fmaf(w0, uplo(u0), a0x); a0y = fmaf(w0, uphi(u0), a0y);
            a1x = fmaf(w1, uplo(u1), a1x); a1y = fmaf(w1, uphi(u1), a1y);
            a2x = fmaf(w2, uplo(u2), a2x); a2y = fmaf(w2, uphi(u2), a2y);
            a3x = fmaf(w3, uplo(u3), a3x); a3y = fmaf(w3, uphi(u3), a3y);
        }
        for (; j < cnt; j += 2) {
            int   s = __shfl(sL, j + p, 64);
            float w = __shfl(wL, j + p, 64);
            unsigned int u = xt32[(size_t)s * 32 + sl];
            a0x = fmaf(w, uplo(u), a0x); a0y = fmaf(w, uphi(u), a0y);
        }
    }
    float tx = (a0x + a1x) + (a2x + a3x);
    float ty = (a0y + a1y) + (a2y + a3y);
    tx += __shfl_xor(tx, 32, 64);
    ty += __shfl_xor(ty, 32, 64);
    // both 32-lane halves now hold all 64 dims -> half-wave reductions exact
    float ssq = hredsum(tx * tx + ty * ty);
    float n  = fmaxf(sqrtf(ssq), EPSV);
    float th = tanhf(n);
    float g  = th / n;
    float nh = fmaxf(th, EPSV);
    if (nh > MAXN) { g *= MAXN / nh; nh = MAXN; }
    float lamg = (artanh_(nh) / nh) * g;
    float t0 = fmaxf(lamg * tx, 0.0f);
    float t1 = fmaxf(lamg * ty, 0.0f);
    float tsq = hredsum(t0 * t0 + t1 * t1);
    float n2  = fmaxf(sqrtf(tsq), EPSV);
    float th2 = tanhf(n2);
    float g2  = th2 / n2;
    float nh2 = fmaxf(th2, EPSV);
    if (nh2 > MAXN) g2 *= MAXN / nh2;
    if (p == 0)
        *(float2*)(out + (size_t)d * 64 + 2 * sl) = make_float2(g2 * t0, g2 * t1);
}

// ===== fallback kernels (round-9 path, used only if ws too small) =====
__global__ __launch_bounds__(256) void hgA_layer1_fp32(
    const float* __restrict__ x, const float* __restrict__ W1,
    const float* __restrict__ b1v, float* __restrict__ xt, int N)
{
    const int tid = threadIdx.x, lane = tid & 63, wv = tid >> 6;
    const int nodeBase = (blockIdx.x * 4 + wv) * 16;
    if (nodeBase >= N) return;
    float y2;
    float hb = bias_point(b1v, lane, &y2);
    float hbv[4];
#pragma unroll
    for (int t = 0; t < 4; ++t) hbv[t] = __shfl(hb, (lane & 15) + 16 * t);
    const int m = lane & 15, q = lane >> 4;
    v4f acc0 = {0,0,0,0}, acc1 = {0,0,0,0}, acc2 = {0,0,0,0}, acc3 = {0,0,0,0};
    float usq = 0.0f;
    const float* arow = x + (size_t)(nodeBase + m) * 256 + q * 8;
#pragma unroll
    for (int s = 0; s < 8; ++s) {
        float af[8];
        *(float4*)(af)     = *(const float4*)(arow + s * 32);
        *(float4*)(af + 4) = *(const float4*)(arow + s * 32 + 4);
#pragma unroll
        for (int j = 0; j < 8; ++j) usq = fmaf(af[j], af[j], usq);
        v8s a = cvt8(af);
        const float* wbase = W1 + (size_t)m * 256 + s * 32 + q * 8;
        float wf[8];
        *(float4*)(wf) = *(const float4*)(wbase);  *(float4*)(wf+4) = *(const float4*)(wbase+4);
        acc0 = __builtin_amdgcn_mfma_f32_16x16x32_bf16(a, cvt8(wf), acc0, 0, 0, 0);
        *(float4*)(wf) = *(const float4*)(wbase+16*256); *(float4*)(wf+4) = *(const float4*)(wbase+16*256+4);
        acc1 = __builtin_amdgcn_mfma_f32_16x16x32_bf16(a, cvt8(wf), acc1, 0, 0, 0);
        *(float4*)(wf) = *(const float4*)(wbase+32*256); *(float4*)(wf+4) = *(const float4*)(wbase+32*256+4);
        acc2 = __builtin_amdgcn_mfma_f32_16x16x32_bf16(a, cvt8(wf), acc2, 0, 0, 0);
        *(float4*)(wf) = *(const float4*)(wbase+48*256); *(float4*)(wf+4) = *(const float4*)(wbase+48*256+4);
        acc3 = __builtin_amdgcn_mfma_f32_16x16x32_bf16(a, cvt8(wf), acc3, 0, 0, 0);
    }
    usq += __shfl_xor(usq, 16, 64);
    usq += __shfl_xor(usq, 32, 64);
    float P[4], Q[4];
#pragma unroll
    for (int r = 0; r < 4; ++r) {
        float s2 = acc0[r]*acc0[r] + acc1[r]*acc1[r] + acc2[r]*acc2[r] + acc3[r]*acc3[r];
        float sh = acc0[r]*hbv[0] + acc1[r]*hbv[1] + acc2[r]*hbv[2] + acc3[r]*hbv[3];
#pragma unroll
        for (int o = 1; o < 16; o <<= 1) { s2 += __shfl_xor(s2, o, 64); sh += __shfl_xor(sh, o, 64); }
        float usq_r = __shfl(usq, q * 4 + r);
        float n  = fmaxf(sqrtf(usq_r), EPSV);
        float th = tanhf(n);
        float gamma = th / n;
        float xn = fmaxf(th, EPSV);
        if (xn > MAXN) { gamma *= MAXN / xn; xn = MAXN; }
        float mxn = fmaxf(gamma * sqrtf(s2), EPSV);
        float rt  = tanhf(mxn / xn * artanh_(xn));
        float k1, x2s, xy;
        if (s2 != 0.0f) {
            k1 = (rt / mxn) * gamma;
            float mvn = fmaxf(fabsf(rt), EPSV);
            if (mvn > MAXN) k1 *= MAXN / mvn;
            float cn = fminf(mvn, MAXN);
            x2s = cn * cn; xy = k1 * sh;
        } else { k1 = 0.0f; x2s = 0.0f; xy = 0.0f; }
        float ca = 1.0f + 2.0f * xy + y2;
        float cb = 1.0f - x2s;
        float den = fmaxf(1.0f + 2.0f * xy + x2s * y2, EPSV);
        float hn2 = ca*ca*x2s + 2.0f*ca*cb*xy + cb*cb*y2;
        float hn = fmaxf(sqrtf(hn2) / den, EPSV);
        float hs = 1.0f;
        if (hn > MAXN) { hs = MAXN / hn; hn = MAXN; }
        float lam = artanh_(hn) / hn;
        P[r] = lam * hs * ca * k1 / den;
        Q[r] = lam * hs * cb / den;
    }
#pragma unroll
    for (int r = 0; r < 4; ++r) {
        float* orow = xt + (size_t)(nodeBase + q * 4 + r) * 64 + m;
        orow[ 0] = P[r] * acc0[r] + Q[r] * hbv[0];
        orow[16] = P[r] * acc1[r] + Q[r] * hbv[1];
        orow[32] = P[r] * acc2[r] + Q[r] * hbv[2];
        orow[48] = P[r] * acc3[r] + Q[r] * hbv[3];
    }
}

__global__ __launch_bounds__(256) void hgA_scatter(
    const int* __restrict__ src, const int* __restrict__ dst,
    const float* __restrict__ ew,
    const float* __restrict__ xt, float* __restrict__ agg, int E)
{
    const int lane = threadIdx.x & 63;
    const long long wid = ((long long)blockIdx.x * blockDim.x + threadIdx.x) >> 6;
    const long long nw = ((long long)gridDim.x * blockDim.x) >> 6;
    for (long long e = wid; e < E; e += nw) {
        int s = src[e], d = dst[e];
        atomicAdd(&agg[(size_t)d * 64 + lane], ew[e] * xt[(size_t)s * 64 + lane]);
    }
}

__global__ __launch_bounds__(256) void hgA_layer2_fb(
    const float* __restrict__ agg,
    const float* __restrict__ W2, const float* __restrict__ b2v,
    float* __restrict__ xt2, int N)
{
    const int lane = threadIdx.x & 63, wv = threadIdx.x >> 6;
    float y2;
    float hb = bias_point(b2v, lane, &y2);
    const int nw = gridDim.x * 4;
    for (int i = blockIdx.x * 4 + wv; i < N; i += nw) {
        float a = agg[(size_t)i * 64 + lane];
        float xn;
        float x2 = agg_transform(a, &xn);
        float acc = 0.0f;
        const float* Wrow = W2 + (size_t)lane * 64;
        for (int s = 0; s < 64; ++s)
            acc = fmaf(__shfl(x2, s), Wrow[s], acc);
        float o = mobius_tail(acc, xn, hb, y2);
        xt2[(size_t)i * 64 + lane] = o;
    }
}

__global__ __launch_bounds__(256) void hgA_final_fb(
    const float* __restrict__ agg, float* __restrict__ out, int N)
{
    const int lane = threadIdx.x & 63, wv = threadIdx.x >> 6;
    const int nw = gridDim.x * 4;
    for (int i = blockIdx.x * 4 + wv; i < N; i += nw) {
        float a = agg[(size_t)i * 64 + lane];
        float xn;
        float o = agg_transform(a, &xn);
        out[(size_t)i * 64 + lane] = o;
    }
}

extern "C" void kernel_launch(void* const* d_in, const int* in_sizes, int n_in,
                              void* d_out, int out_size, void* d_ws, size_t ws_size,
                              hipStream_t stream)
{
    const float* x  = (const float*)d_in[0];
    const int* src  = (const int*)d_in[1];
    const int* dst  = (const int*)d_in[2];
    const float* ew = (const float*)d_in[3];
    const float* W1 = (const float*)d_in[4];
    const float* b1 = (const float*)d_in[5];
    const float* W2 = (const float*)d_in[6];
    const float* b2 = (const float*)d_in[7];

    const int Dd = in_sizes[5];            // 64
    const int Ff = in_sizes[4] / Dd;       // 256
    const int N  = in_sizes[0] / Ff;       // 80000
    const int E  = in_sizes[1];            // 1280000

    float* out = (float*)d_out;
    float* agg = (float*)d_out;            // CSR path: fp32 agg lives in d_out

    // ws layouts:
    // tier A: [xtb bf16 2*N*64][deg N][rowst N+1][cursor N][rank E][pad][csr 8E]
    // tier B: [xtb bf16 2*N*64][deg N][rowst N+1][cursor N][pad][csr 8E]
    bfu*  xtb    = (bfu*)d_ws;
    size_t xtb_b = (size_t)N * Dd * 2;
    int*  deg    = (int*)((char*)d_ws + xtb_b);
    int*  rowst  = deg + N;
    int*  cursor = rowst + (N + 1);
    int*  rank   = cursor + N;
    size_t csr_offA = (xtb_b + ((size_t)(3 * N + 1) + (size_t)E) * 4 + 7) & ~(size_t)7;
    size_t csr_offB = (xtb_b + (size_t)(3 * N + 1) * 4 + 7) & ~(size_t)7;
    const size_t needA = csr_offA + (size_t)E * 8;
    const size_t needB = csr_offB + (size_t)E * 8;

    const int blkT = (N + 63) / 64;        // wave per 16 nodes
    const int blkG = (N + 3) / 4;          // wave per dst node
    const int n4 = (N * Dd) / 4;

    if (ws_size >= needA) {
        int2* csr = (int2*)((char*)d_ws + csr_offA);
        const int L1A = blkT < 512 ? blkT : 512;   // layer1 bids under scan
        const int nl  = blkT - L1A;                // layer1 bids under fill
        hgA_zero_i32  <<<128,  256, 0, stream>>>(deg, N);
        hgA_count_rank<<<2048, 256, 0, stream>>>(dst, deg, rank, E);
        hgA_scan_l1   <<<1 + (L1A + 3) / 4, 1024, 0, stream>>>(
            deg, rowst, cursor, N, x, W1, b1, xtb, L1A);
        hgA_fillr_layer1<<<blkT + nl, 256, 0, stream>>>(
            src, dst, ew, rank, rowst, csr, E, blkT, nl, L1A, x, W1, b1, xtb, N);
        hgA_gather     <<<blkG, 256, 0, stream>>>(rowst, csr, xtb, agg, N);
        hgA_layer2_mfma<<<blkT, 256, 0, stream>>>(agg, W2, b2, xtb, N);
        hgA_gather_out <<<blkG, 256, 0, stream>>>(rowst, csr, xtb, out, N);
    } else if (ws_size >= needB) {
        // round-10 proven path (atomic cursor fill) + paired gathers
        int2* csr = (int2*)((char*)d_ws + csr_offB);
        const int fillBlocks = 2048;
        hgA_zero_i32   <<<128,  256, 0, stream>>>(deg, N);
        hgA_count      <<<2048, 256, 0, stream>>>(dst, deg, E);
        hgA_scan_l1    <<<1,   1024, 0, stream>>>(
            deg, rowst, cursor, N, x, W1, b1, xtb, 0);
        hgA_fill_layer1<<<fillBlocks + blkT, 256, 0, stream>>>(
            src, dst, ew, cursor, csr, E, fillBlocks, x, W1, b1, xtb, N);
        hgA_gather     <<<blkG, 256, 0, stream>>>(rowst, csr, xtb, agg, N);
        hgA_layer2_mfma<<<blkT, 256, 0, stream>>>(agg, W2, b2, xtb, N);
        hgA_gather_out <<<blkG, 256, 0, stream>>>(rowst, csr, xtb, out, N);
    } else {
        // round-9 fallback: xt fp32 in d_out, agg fp32 in ws
        float* xt_fb  = (float*)d_out;
        float* agg_fb = (float*)d_ws;
        hgA_layer1_fp32<<<blkT, 256, 0, stream>>>(x, W1, b1, xt_fb, N);
        hgA_zero     <<<1024,  256, 0, stream>>>(agg_fb, n4);
        hgA_scatter  <<<16384, 256, 0, stream>>>(src, dst, ew, xt_fb, agg_fb, E);
        hgA_layer2_fb<<<2048,  256, 0, stream>>>(agg_fb, W2, b2, xt_fb, N);
        hgA_zero     <<<1024,  256, 0, stream>>>(agg_fb, n4);
        hgA_scatter  <<<16384, 256, 0, stream>>>(src, dst, ew, xt_fb, agg_fb, E);
        hgA_final_fb <<<2048,  256, 0, stream>>>(agg_fb, out, N);
    }
}